// Round 2
// baseline (541.692 us; speedup 1.0000x reference)
//
#include <hip/hip_runtime.h>

// Problem constants (GraphNet_41944650613153)
#define NN    156            // real nodes per graph
#define NP    160            // padded nodes (MFMA tiles of 16)
#define CN    128            // channels
#define K0    301            // layer-0 input channels
#define KP0   320            // padded K for layer 0
#define BATCH 1024

#define W0_OFF 0
#define W1_OFF (128 * KP0)
#define W2_OFF (128 * KP0 + 128 * 128)

typedef __attribute__((ext_vector_type(8))) short bf16x8;  // 8 bf16 (4 VGPRs)
typedef __attribute__((ext_vector_type(4))) float f32x4;   // 4 fp32

// Pre-transposed hi/lo-split weights Wt[n][k]=W[k][n] (zero-padded k) and the
// dense normalized adjacency Adj[dst][src] (shared by all graphs, L2-resident).
__device__ __align__(16) ushort g_WtH[128 * (KP0 + 128 + 128)];
__device__ __align__(16) ushort g_WtL[128 * (KP0 + 128 + 128)];
__device__ __align__(16) ushort g_AdjH[NP * NP];
__device__ __align__(16) ushort g_AdjL[NP * NP];

__device__ __forceinline__ ushort bf16_rne(float f) {
    union { float f; uint32_t u; } v; v.f = f;
    return (ushort)((v.u + 0x7FFFu + ((v.u >> 16) & 1u)) >> 16);
}
__device__ __forceinline__ float bf16_f(ushort h) {
    union { float f; uint32_t u; } v; v.u = ((uint32_t)h) << 16; return v.f;
}
__device__ __forceinline__ ushort bf16_trunc(float f) {
    union { float f; uint32_t u; } v; v.f = f;
    return (ushort)(v.u >> 16);
}

// ---------------------------------------------------------------------------
// prep (block 0): dense normalized adjacency with self-loops and duplicate-
// edge multiplicity. Adj[dst][src] = m * dinv[src] * dinv[dst]; pads = 0.
// wt (blocks 1..288): all three weight transposes + hi/lo splits.
// ---------------------------------------------------------------------------
__global__ __launch_bounds__(256) void prep_wt(const int* __restrict__ ei, int E,
        const float* __restrict__ W0, const float* __restrict__ W1,
        const float* __restrict__ W2) {
    __shared__ float adjf[NP * NP];      // 102,400 B (block 0 only)
    __shared__ int   cnt[NP];
    __shared__ float dinv_s[NP];
    const int t = threadIdx.x;
    if (blockIdx.x == 0) {
        for (int i = t; i < NP * NP; i += 256) adjf[i] = 0.f;
        for (int n = t; n < NP; n += 256) cnt[n] = (n < NN) ? 1 : 0;   // self loop
        __syncthreads();
        for (int e = t; e < E; e += 256) atomicAdd(&cnt[ei[E + e]], 1);
        __syncthreads();
        for (int n = t; n < NP; n += 256)
            dinv_s[n] = (cnt[n] > 0) ? rsqrtf((float)cnt[n]) : 0.f;
        __syncthreads();
        for (int e = t; e < E; e += 256) {
            const int r = ei[e], c = ei[E + e];
            atomicAdd(&adjf[c * NP + r], dinv_s[r] * dinv_s[c]);
        }
        for (int n = t; n < NN; n += 256)
            atomicAdd(&adjf[n * NP + n], dinv_s[n] * dinv_s[n]);
        __syncthreads();
        for (int i = t; i < NP * NP; i += 256) {
            const float v = adjf[i];
            const ushort h = bf16_rne(v);
            g_AdjH[i] = h;
            g_AdjL[i] = bf16_trunc(v - bf16_f(h));
        }
    } else {
        const int id = (blockIdx.x - 1) * 256 + t;   // exact: 288*256
        const float* W; int K, KP, woff, local;
        if (id < 128 * KP0)              { W = W0; K = K0;  KP = KP0; woff = W0_OFF; local = id; }
        else if (id < 128 * (KP0 + 128)) { W = W1; K = 128; KP = 128; woff = W1_OFF; local = id - 128 * KP0; }
        else                             { W = W2; K = 128; KP = 128; woff = W2_OFF; local = id - 128 * (KP0 + 128); }
        const int n = local & 127, k = local >> 7;
        const float f = (k < K) ? W[(size_t)k * CN + n] : 0.f;
        const ushort h = bf16_rne(f);
        g_WtH[woff + n * KP + k] = h;
        g_WtL[woff + n * KP + k] = bf16_trunc(f - bf16_f(h));
    }
}

// ---------------------------------------------------------------------------
// Fully fused 3-layer GCN, one graph per block, 8 waves, 2 blocks/CU
// (4 waves/SIMD — double round-1's latency hiding; per-wave work halved).
//
// LDS (81,920 B): two 40,960 B planes (hi / lo) that alternate roles:
//   As (layer-0 x staging, dbuf) : [seg 0..3][row 0..159][8 bf16]  (2 x 10,240)
//   tT (t transposed)            : [seg 0..19][ch 0..127][8 bf16]  (40,960)
//   h  (activations)             : [seg 0..15][row 0..159][8 bf16] (40,960)
//
// Wave partition:
//   GEMM (t = A@W, 160x128): wave (wr,wc) = (wave>>2, wave&3) owns rows
//     [wr*80, wr*80+80) x chans [wc*32, wc*32+32): acc[5][2].
//   AGG (og = tT@Adj^T, 128x160): wave owns chans [wave*16, wave*16+16)
//     x all 160 dst: og[10].  AGG uses 3 split products (lo*lo dropped,
//     ~2^-16 relative — 256x below measured absmax).
// ---------------------------------------------------------------------------
__global__ __launch_bounds__(512, 4) void fused_all(
        const float* __restrict__ x,
        const float* __restrict__ cb0, const float* __restrict__ bw0, const float* __restrict__ bb0,
        const float* __restrict__ cb1, const float* __restrict__ bw1, const float* __restrict__ bb1,
        const float* __restrict__ cb2, float* __restrict__ out) {
    __shared__ __align__(16) uint8_t smem[81920];
    uint8_t* const pH = smem;
    uint8_t* const pL = smem + 40960;

    const int t = threadIdx.x;
    const int lane = t & 63, wave = t >> 6;
    const int quad = lane >> 4, l15 = lane & 15;
    const int rb = (wave >> 2) * 80;     // GEMM row base (src nodes)
    const int cbs = (wave & 3) * 32;     // GEMM channel base
    const int ch0 = wave * 16;           // AGG channel base
    const size_t arow0 = (size_t)blockIdx.x * NN;

    f32x4 acc[5][2];   // GEMM result t: 80 rows x 32 chans per wave
    f32x4 og[10];      // AGG result: 16 chans x 160 dst per wave

    // ---- layer-0 staging: x fp32 -> split planes (shared conversion) ----
    const int kp  = (t & 15) * 2;   // column pair within 32-wide k tile
    const int r0s = t >> 4;         // base row (0..31)
    float sv0[5], sv1[5];

    auto stage_load = [&](int kt) {
        const int kk = kt * 32 + kp;
#pragma unroll
        for (int s = 0; s < 5; s++) {
            const int r  = r0s + s * 32;
            const int rc = (r < NN) ? r : (NN - 1);          // clamp pad rows
            const size_t abase = (arow0 + rc) * (size_t)K0;
            sv0[s] = (kk < K0)     ? x[abase + kk]     : 0.f;
            sv1[s] = (kk + 1 < K0) ? x[abase + kk + 1] : 0.f;
        }
    };
    auto stage_write = [&](int buf) {
        const int segoff = buf * 10240 + (((kp >> 3) * NP) << 4) + (kp & 7) * 2;
#pragma unroll
        for (int s = 0; s < 5; s++) {
            const int r = r0s + s * 32;
            const int off = segoff + (r << 4);
            const ushort h0 = bf16_rne(sv0[s]), h1 = bf16_rne(sv1[s]);
            *(ushort2*)(pH + off) = make_ushort2(h0, h1);
            *(ushort2*)(pL + off) = make_ushort2(bf16_trunc(sv0[s] - bf16_f(h0)),
                                                 bf16_trunc(sv1[s] - bf16_f(h1)));
        }
    };

    auto gemm_l0_tile = [&](int kt, int buf) {
        bf16x8 bH[2], bL[2];
#pragma unroll
        for (int j = 0; j < 2; j++) {
            const int wi = W0_OFF + (cbs + j * 16 + l15) * KP0 + kt * 32 + quad * 8;
            bH[j] = *(const bf16x8*)&g_WtH[wi];
            bL[j] = *(const bf16x8*)&g_WtL[wi];
        }
#pragma unroll
        for (int i = 0; i < 5; i++) {
            const int off = buf * 10240 + ((quad * NP + rb + i * 16 + l15) << 4);
            const bf16x8 aH = *(const bf16x8*)(pH + off);
            const bf16x8 aL = *(const bf16x8*)(pL + off);
#pragma unroll
            for (int j = 0; j < 2; j++) {
                acc[i][j] = __builtin_amdgcn_mfma_f32_16x16x32_bf16(aH, bH[j], acc[i][j], 0, 0, 0);
                acc[i][j] = __builtin_amdgcn_mfma_f32_16x16x32_bf16(aH, bL[j], acc[i][j], 0, 0, 0);
                acc[i][j] = __builtin_amdgcn_mfma_f32_16x16x32_bf16(aL, bH[j], acc[i][j], 0, 0, 0);
            }
        }
    };

    auto gemm_h = [&](int woff) {
#pragma unroll
        for (int i = 0; i < 5; i++)
#pragma unroll
            for (int j = 0; j < 2; j++) acc[i][j] = (f32x4){0.f, 0.f, 0.f, 0.f};
        for (int kt = 0; kt < 4; kt++) {
            bf16x8 bH[2], bL[2];
#pragma unroll
            for (int j = 0; j < 2; j++) {
                const int wi = woff + (cbs + j * 16 + l15) * CN + kt * 32 + quad * 8;
                bH[j] = *(const bf16x8*)&g_WtH[wi];
                bL[j] = *(const bf16x8*)&g_WtL[wi];
            }
#pragma unroll
            for (int i = 0; i < 5; i++) {
                const int off = ((kt * 4 + quad) * NP + rb + i * 16 + l15) << 4;
                const bf16x8 aH = *(const bf16x8*)(pH + off);
                const bf16x8 aL = *(const bf16x8*)(pL + off);
#pragma unroll
                for (int j = 0; j < 2; j++) {
                    acc[i][j] = __builtin_amdgcn_mfma_f32_16x16x32_bf16(aH, bH[j], acc[i][j], 0, 0, 0);
                    acc[i][j] = __builtin_amdgcn_mfma_f32_16x16x32_bf16(aH, bL[j], acc[i][j], 0, 0, 0);
                    acc[i][j] = __builtin_amdgcn_mfma_f32_16x16x32_bf16(aL, bH[j], acc[i][j], 0, 0, 0);
                }
            }
        }
    };

    // t (C/D frag: col=ch=l15, row=src=quad*4+rg) -> tT planes [src-seg][ch][8]
    auto write_tT = [&]() {
#pragma unroll
        for (int i = 0; i < 5; i++)
#pragma unroll
            for (int j = 0; j < 2; j++) {
                const int ch = cbs + j * 16 + l15;
                const int s0 = rb + i * 16 + quad * 4;
                const int off = (((s0 >> 3) * CN + ch) << 4) + (s0 & 7) * 2;
                ushort4 hs, ls;
#pragma unroll
                for (int rg = 0; rg < 4; rg++) {
                    const float v = acc[i][j][rg];
                    const ushort h = bf16_rne(v);
                    (&hs.x)[rg] = h;
                    (&ls.x)[rg] = bf16_trunc(v - bf16_f(h));
                }
                *(ushort4*)(pH + off) = hs;
                *(ushort4*)(pL + off) = ls;
            }
    };

    // og[ch][dst] = sum_src tT[ch][src] * Adj[dst][src]  (3-product split)
    auto do_agg = [&]() {
#pragma unroll
        for (int nj = 0; nj < 10; nj++) og[nj] = (f32x4){0.f, 0.f, 0.f, 0.f};
        for (int k2 = 0; k2 < 5; k2++) {
            const int offA = ((k2 * 4 + quad) * CN + ch0 + l15) << 4;
            const bf16x8 tAH = *(const bf16x8*)(pH + offA);
            const bf16x8 tAL = *(const bf16x8*)(pL + offA);
#pragma unroll
            for (int nj = 0; nj < 10; nj++) {
                const int ai = (nj * 16 + l15) * NP + k2 * 32 + quad * 8;
                const bf16x8 gH = *(const bf16x8*)&g_AdjH[ai];
                const bf16x8 gL = *(const bf16x8*)&g_AdjL[ai];
                og[nj] = __builtin_amdgcn_mfma_f32_16x16x32_bf16(tAH, gH, og[nj], 0, 0, 0);
                og[nj] = __builtin_amdgcn_mfma_f32_16x16x32_bf16(tAH, gL, og[nj], 0, 0, 0);
                og[nj] = __builtin_amdgcn_mfma_f32_16x16x32_bf16(tAL, gH, og[nj], 0, 0, 0);
            }
        }
    };

    // og (frag: col=node=l15, row=ch=quad*4+rg) -> relu(bn(.+cb)) -> h planes
    auto write_h = [&](const float* cb, const float* bw, const float* bb) {
        const float inv = rsqrtf(1.f + 1e-5f);
        const int c0 = ch0 + quad * 4;
        const float4 cbv = *(const float4*)&cb[c0];
        const float4 bwv = *(const float4*)&bw[c0];
        const float4 bbv = *(const float4*)&bb[c0];
#pragma unroll
        for (int nj = 0; nj < 10; nj++) {
            const int node = nj * 16 + l15;
            const int off = (((c0 >> 3) * NP + node) << 4) + (c0 & 7) * 2;
            ushort4 hs, ls;
#pragma unroll
            for (int rg = 0; rg < 4; rg++) {
                float v = og[nj][rg] + (&cbv.x)[rg];
                v = fmaxf(fmaf(v, (&bwv.x)[rg] * inv, (&bbv.x)[rg]), 0.f);
                const ushort h = bf16_rne(v);
                (&hs.x)[rg] = h;
                (&ls.x)[rg] = bf16_trunc(v - bf16_f(h));
            }
            *(ushort4*)(pH + off) = hs;
            *(ushort4*)(pL + off) = ls;
        }
    };

    auto write_out = [&](const float* cb) {
        const int c0 = ch0 + quad * 4;
        const float4 cbv = *(const float4*)&cb[c0];
#pragma unroll
        for (int nj = 0; nj < 10; nj++) {
            const int node = nj * 16 + l15;
            if (node < NN) {
                float4 o;
#pragma unroll
                for (int rg = 0; rg < 4; rg++)
                    (&o.x)[rg] = og[nj][rg] + (&cbv.x)[rg];
                *(float4*)&out[(arow0 + node) * CN + c0] = o;
            }
        }
    };

    // =================== layer 0 ===================
#pragma unroll
    for (int i = 0; i < 5; i++)
#pragma unroll
        for (int j = 0; j < 2; j++) acc[i][j] = (f32x4){0.f, 0.f, 0.f, 0.f};
    stage_load(0);
    stage_write(0);
    __syncthreads();
    for (int kt = 0; kt < 10; kt++) {       // dbuf: loads early, converts late
        if (kt < 9) stage_load(kt + 1);
        gemm_l0_tile(kt, kt & 1);
        if (kt < 9) stage_write((kt + 1) & 1);
        __syncthreads();
    }
    write_tT();
    __syncthreads();
    do_agg();
    __syncthreads();
    write_h(cb0, bw0, bb0);
    __syncthreads();
    // =================== layer 1 ===================
    gemm_h(W1_OFF);
    __syncthreads();
    write_tT();
    __syncthreads();
    do_agg();
    __syncthreads();
    write_h(cb1, bw1, bb1);
    __syncthreads();
    // =================== layer 2 ===================
    gemm_h(W2_OFF);
    __syncthreads();
    write_tT();
    __syncthreads();
    do_agg();
    write_out(cb2);
}

// ---------------------------------------------------------------------------
// Orchestration: prep_wt (Adj + weight planes) + one fused kernel.
// ---------------------------------------------------------------------------
extern "C" void kernel_launch(void* const* d_in, const int* in_sizes, int n_in,
                              void* d_out, int out_size, void* d_ws, size_t ws_size,
                              hipStream_t stream) {
    const float* x    = (const float*)d_in[0];
    const int*   ei   = (const int*)  d_in[1];
    const float* W0   = (const float*)d_in[2];
    const float* b0   = (const float*)d_in[3];
    const float* bnw0 = (const float*)d_in[4];
    const float* bnb0 = (const float*)d_in[5];
    const float* W1   = (const float*)d_in[6];
    const float* b1   = (const float*)d_in[7];
    const float* bnw1 = (const float*)d_in[8];
    const float* bnb1 = (const float*)d_in[9];
    const float* W2   = (const float*)d_in[10];
    const float* b2   = (const float*)d_in[11];
    float* out = (float*)d_out;

    const int E = in_sizes[1] / 2;

    prep_wt<<<289, 256, 0, stream>>>(ei, E, W0, W1, W2);
    fused_all<<<BATCH, 512, 0, stream>>>(x, b0, bnw0, bnb0,
                                         b1, bnw1, bnb1, b2, out);
}

// Round 3
// 448.499 us; speedup vs baseline: 1.2078x; 1.2078x over previous
//
#include <hip/hip_runtime.h>

// Problem constants (GraphNet_41944650613153)
#define NN    156            // real nodes per graph
#define NP    160            // padded nodes (MFMA tiles of 16)
#define CN    128            // channels
#define K0    301            // layer-0 input channels
#define KP0   320            // padded K for layer 0
#define BATCH 1024

#define W0_OFF 0
#define W1_OFF (128 * KP0)
#define W2_OFF (128 * KP0 + 128 * 128)

typedef __attribute__((ext_vector_type(8))) short bf16x8;  // 8 bf16 (4 VGPRs)
typedef __attribute__((ext_vector_type(4))) float f32x4;   // 4 fp32

// Pre-transposed hi/lo-split weights Wt[n][k]=W[k][n] (zero-padded k, BN scale
// folded into W0/W1 columns) and the dense normalized adjacency Adj[dst][src]
// (shared by all graphs, L2-resident).
__device__ __align__(16) ushort g_WtH[128 * (KP0 + 128 + 128)];
__device__ __align__(16) ushort g_WtL[128 * (KP0 + 128 + 128)];
__device__ __align__(16) ushort g_AdjH[NP * NP];
__device__ __align__(16) ushort g_AdjL[NP * NP];

__device__ __forceinline__ ushort bf16_rne(float f) {
    return __builtin_bit_cast(ushort, (__bf16)f);        // HW RNE convert
}
__device__ __forceinline__ float bf16_f(ushort h) {
    return __builtin_bit_cast(float, (uint32_t)h << 16);
}
__device__ __forceinline__ ushort bf16_lo(float f, ushort h) {
    return (ushort)(__builtin_bit_cast(uint32_t, f - bf16_f(h)) >> 16);
}

// Barrier with LDS-only drain: keeps global (vmem) prefetches in flight.
// Safe here: all cross-wave communication in fused_all goes through LDS.
__device__ __forceinline__ void barrier_lgkm() {
    asm volatile("s_waitcnt lgkmcnt(0)\n\ts_barrier" ::: "memory");
}

// ---------------------------------------------------------------------------
// prep (block 0): dense normalized adjacency with self-loops and duplicate-
// edge multiplicity. Adj[dst][src] = m * dinv[src] * dinv[dst]; pads = 0.
// wt (blocks 1..288): weight transpose + hi/lo split, BN scale folded in.
// ---------------------------------------------------------------------------
__global__ __launch_bounds__(256) void prep_wt(const int* __restrict__ ei, int E,
        const float* __restrict__ W0, const float* __restrict__ W1,
        const float* __restrict__ W2, const float* __restrict__ bw0,
        const float* __restrict__ bw1) {
    __shared__ float adjf[NP * NP];      // 102,400 B (block 0 only)
    __shared__ int   cnt[NP];
    __shared__ float dinv_s[NP];
    const int t = threadIdx.x;
    if (blockIdx.x == 0) {
        for (int i = t; i < NP * NP; i += 256) adjf[i] = 0.f;
        for (int n = t; n < NP; n += 256) cnt[n] = (n < NN) ? 1 : 0;   // self loop
        __syncthreads();
        for (int e = t; e < E; e += 256) atomicAdd(&cnt[ei[E + e]], 1);
        __syncthreads();
        for (int n = t; n < NP; n += 256)
            dinv_s[n] = (cnt[n] > 0) ? rsqrtf((float)cnt[n]) : 0.f;
        __syncthreads();
        for (int e = t; e < E; e += 256) {
            const int r = ei[e], c = ei[E + e];
            atomicAdd(&adjf[c * NP + r], dinv_s[r] * dinv_s[c]);
        }
        for (int n = t; n < NN; n += 256)
            atomicAdd(&adjf[n * NP + n], dinv_s[n] * dinv_s[n]);
        __syncthreads();
        for (int i = t; i < NP * NP; i += 256) {
            const float v = adjf[i];
            const ushort h = bf16_rne(v);
            g_AdjH[i] = h;
            g_AdjL[i] = bf16_lo(v, h);
        }
    } else {
        const int id = (blockIdx.x - 1) * 256 + t;   // exact: 288*256
        const float* W; int K, KP, woff, local;
        if (id < 128 * KP0)              { W = W0; K = K0;  KP = KP0; woff = W0_OFF; local = id; }
        else if (id < 128 * (KP0 + 128)) { W = W1; K = 128; KP = 128; woff = W1_OFF; local = id - 128 * KP0; }
        else                             { W = W2; K = 128; KP = 128; woff = W2_OFF; local = id - 128 * (KP0 + 128); }
        const int n = local & 127, k = local >> 7;
        const float inv = rsqrtf(1.f + 1e-5f);
        float s = 1.f;                                   // BN scale folded into W
        if (woff == W0_OFF) s = bw0[n] * inv;
        else if (woff == W1_OFF) s = bw1[n] * inv;
        const float f = (k < K) ? W[(size_t)k * CN + n] * s : 0.f;
        const ushort h = bf16_rne(f);
        g_WtH[woff + n * KP + k] = h;
        g_WtL[woff + n * KP + k] = bf16_lo(f, h);
    }
}

// ---------------------------------------------------------------------------
// Fully fused 3-layer GCN, one graph per block, 4 waves, 2 blocks/CU.
//
// LDS (81,920 B): two 40,960 B planes (hi / lo) that alternate roles:
//   As (layer-0 x staging, dbuf) : [seg 0..3][row 0..159][8 bf16]  (2 x 10,240)
//   tT (t transposed)            : [seg 0..19][ch 0..127][8 bf16]  (40,960)
//   h  (activations)             : [seg 0..15][row 0..159][8 bf16] (40,960)
//
// Wave partition (2D in both phases, maximizing B-fragment reuse):
//   GEMM (t = A@W, 160x128): wave owns rows [wr,wr+80) x chans [wc,wc+64):
//     acc[5][4]; W frags double-buffered across kt, issued a phase early.
//   AGG (og = tT@Adj^T): wave owns chans [ac,ac+64) x dst [ad,ad+80):
//     og[4][5]; Adj frags in a ring-4 register prefetch (~230 cy ahead),
//     first 4 issued BEFORE the barrier (barriers don't drain vmcnt).
//   AGG uses 3 split products (lo*lo dropped).
// ---------------------------------------------------------------------------
__global__ __launch_bounds__(256, 2) void fused_all(
        const float* __restrict__ x,
        const float* __restrict__ cb0, const float* __restrict__ bw0, const float* __restrict__ bb0,
        const float* __restrict__ cb1, const float* __restrict__ bw1, const float* __restrict__ bb1,
        const float* __restrict__ cb2, float* __restrict__ out) {
    __shared__ __align__(16) uint8_t smem[81920];
    uint8_t* const pH = smem;
    uint8_t* const pL = smem + 40960;

    const int t = threadIdx.x;
    const int lane = t & 63, wave = t >> 6;
    const int quad = lane >> 4, l15 = lane & 15;
    const int wr = (wave >> 1) * 80;      // GEMM row base (src nodes)
    const int wc = (wave & 1) * 64;       // GEMM chan base
    const int ac = (wave & 1) * 64;       // AGG chan base
    const int ad = (wave >> 1) * 80;      // AGG dst base
    const size_t arow0 = (size_t)blockIdx.x * NN;

    f32x4 acc[5][4];   // GEMM result t: 80 rows x 64 chans per wave
    f32x4 og[4][5];    // AGG result: 64 chans x 80 dst per wave

    // ---- layer-0 staging: x fp32 -> split planes (shared conversion) ----
    const int kp  = (t & 15) * 2;   // column pair within 32-wide k tile
    const int r0s = t >> 4;         // base row (0..15)
    float sv0[10], sv1[10];

    auto stage_load = [&](int kt) {
        const int kk = kt * 32 + kp;
#pragma unroll
        for (int s = 0; s < 10; s++) {
            const int r  = r0s + s * 16;
            const int rc = (r < NN) ? r : (NN - 1);          // clamp pad rows
            const size_t abase = (arow0 + rc) * (size_t)K0;
            sv0[s] = (kk < K0)     ? x[abase + kk]     : 0.f;
            sv1[s] = (kk + 1 < K0) ? x[abase + kk + 1] : 0.f;
        }
    };
    auto stage_write = [&](int buf) {
        const int segoff = buf * 10240 + (((kp >> 3) * NP) << 4) + (kp & 7) * 2;
#pragma unroll
        for (int s = 0; s < 10; s++) {
            const int off = segoff + ((r0s + s * 16) << 4);
            const ushort h0 = bf16_rne(sv0[s]), h1 = bf16_rne(sv1[s]);
            *(ushort2*)(pH + off) = make_ushort2(h0, h1);
            *(ushort2*)(pL + off) = make_ushort2(bf16_lo(sv0[s], h0), bf16_lo(sv1[s], h1));
        }
    };

    // ---- W fragments: double-buffered registers, loaded from L2 ----
    bf16x8 wbH[2][4], wbL[2][4];
    auto loadW = [&](int woff, int KP, int kt, int sl) {
#pragma unroll
        for (int j = 0; j < 4; j++) {
            const int wi = woff + (wc + j * 16 + l15) * KP + kt * 32 + quad * 8;
            wbH[sl][j] = *(const bf16x8*)&g_WtH[wi];
            wbL[sl][j] = *(const bf16x8*)&g_WtL[wi];
        }
    };

    // ---- Adj fragments: ring-4 register prefetch ----
    bf16x8 gjH[4], gjL[4];
    auto adj_pf = [&](int step) {               // step is unroll-constant
        const int k2 = step / 5, nj = step % 5;
        const int ai = (ad + nj * 16 + l15) * NP + k2 * 32 + quad * 8;
        gjH[step & 3] = *(const bf16x8*)&g_AdjH[ai];
        gjL[step & 3] = *(const bf16x8*)&g_AdjL[ai];
    };

    auto gemm_l0_tile = [&](int buf, int sl) {
#pragma unroll
        for (int i = 0; i < 5; i++) {
            const int off = buf * 10240 + ((quad * NP + wr + i * 16 + l15) << 4);
            const bf16x8 aH = *(const bf16x8*)(pH + off);
            const bf16x8 aL = *(const bf16x8*)(pL + off);
#pragma unroll
            for (int j = 0; j < 4; j++) {
                acc[i][j] = __builtin_amdgcn_mfma_f32_16x16x32_bf16(aH, wbH[sl][j], acc[i][j], 0, 0, 0);
                acc[i][j] = __builtin_amdgcn_mfma_f32_16x16x32_bf16(aH, wbL[sl][j], acc[i][j], 0, 0, 0);
                acc[i][j] = __builtin_amdgcn_mfma_f32_16x16x32_bf16(aL, wbH[sl][j], acc[i][j], 0, 0, 0);
            }
        }
    };

    auto gemm_h = [&](int woff) {   // caller issued loadW(woff,CN,0,0) pre-barrier
#pragma unroll
        for (int i = 0; i < 5; i++)
#pragma unroll
            for (int j = 0; j < 4; j++) acc[i][j] = (f32x4){0.f, 0.f, 0.f, 0.f};
#pragma unroll
        for (int kt = 0; kt < 4; kt++) {
            if (kt < 3) loadW(woff, CN, kt + 1, (kt + 1) & 1);
#pragma unroll
            for (int i = 0; i < 5; i++) {
                const int off = ((kt * 4 + quad) * NP + wr + i * 16 + l15) << 4;
                const bf16x8 aH = *(const bf16x8*)(pH + off);
                const bf16x8 aL = *(const bf16x8*)(pL + off);
#pragma unroll
                for (int j = 0; j < 4; j++) {
                    acc[i][j] = __builtin_amdgcn_mfma_f32_16x16x32_bf16(aH, wbH[kt & 1][j], acc[i][j], 0, 0, 0);
                    acc[i][j] = __builtin_amdgcn_mfma_f32_16x16x32_bf16(aH, wbL[kt & 1][j], acc[i][j], 0, 0, 0);
                    acc[i][j] = __builtin_amdgcn_mfma_f32_16x16x32_bf16(aL, wbH[kt & 1][j], acc[i][j], 0, 0, 0);
                }
            }
        }
    };

    // t (C/D frag: col=ch=l15, row=src=quad*4+rg) -> tT planes [src-seg][ch][8]
    auto write_tT = [&]() {
#pragma unroll
        for (int i = 0; i < 5; i++)
#pragma unroll
            for (int j = 0; j < 4; j++) {
                const int ch = wc + j * 16 + l15;
                const int s0 = wr + i * 16 + quad * 4;
                const int off = (((s0 >> 3) * CN + ch) << 4) + (s0 & 7) * 2;
                ushort4 hs, ls;
#pragma unroll
                for (int rg = 0; rg < 4; rg++) {
                    const float v = acc[i][j][rg];
                    const ushort h = bf16_rne(v);
                    (&hs.x)[rg] = h;
                    (&ls.x)[rg] = bf16_lo(v, h);
                }
                *(ushort4*)(pH + off) = hs;
                *(ushort4*)(pL + off) = ls;
            }
    };

    // og[ch][dst] = sum_src tT[ch][src] * Adj[dst][src]  (3-product split)
    auto do_agg = [&]() {
#pragma unroll
        for (int mi = 0; mi < 4; mi++)
#pragma unroll
            for (int nj = 0; nj < 5; nj++) og[mi][nj] = (f32x4){0.f, 0.f, 0.f, 0.f};
#pragma unroll
        for (int k2 = 0; k2 < 5; k2++) {
            bf16x8 taH[4], taL[4];
#pragma unroll
            for (int mi = 0; mi < 4; mi++) {
                const int off = ((k2 * 4 + quad) * CN + ac + mi * 16 + l15) << 4;
                taH[mi] = *(const bf16x8*)(pH + off);
                taL[mi] = *(const bf16x8*)(pL + off);
            }
#pragma unroll
            for (int nj = 0; nj < 5; nj++) {
                const int step = k2 * 5 + nj, slot = step & 3;
#pragma unroll
                for (int mi = 0; mi < 4; mi++) {
                    og[mi][nj] = __builtin_amdgcn_mfma_f32_16x16x32_bf16(taH[mi], gjH[slot], og[mi][nj], 0, 0, 0);
                    og[mi][nj] = __builtin_amdgcn_mfma_f32_16x16x32_bf16(taH[mi], gjL[slot], og[mi][nj], 0, 0, 0);
                    og[mi][nj] = __builtin_amdgcn_mfma_f32_16x16x32_bf16(taL[mi], gjH[slot], og[mi][nj], 0, 0, 0);
                }
                if (step + 4 < 25) adj_pf(step + 4);   // refill slot for step+4
            }
        }
    };

    // og (frag: col=node=l15, row=ch=quad*4+rg) -> relu(og + (cb*s+bb)) -> h
    auto write_h = [&](const float* cb, const float* bw, const float* bb) {
        const float inv = rsqrtf(1.f + 1e-5f);
#pragma unroll
        for (int mi = 0; mi < 4; mi++) {
            const int c0 = ac + mi * 16 + quad * 4;
            const float4 cbv = *(const float4*)&cb[c0];
            const float4 bwv = *(const float4*)&bw[c0];
            const float4 bbv = *(const float4*)&bb[c0];
            float cbf[4];
#pragma unroll
            for (int rg = 0; rg < 4; rg++)
                cbf[rg] = fmaf((&cbv.x)[rg], (&bwv.x)[rg] * inv, (&bbv.x)[rg]);
#pragma unroll
            for (int nj = 0; nj < 5; nj++) {
                const int node = ad + nj * 16 + l15;
                const int off = (((c0 >> 3) * NP + node) << 4) + (c0 & 7) * 2;
                ushort4 hs, ls;
#pragma unroll
                for (int rg = 0; rg < 4; rg++) {
                    const float v = fmaxf(og[mi][nj][rg] + cbf[rg], 0.f);
                    const ushort h = bf16_rne(v);
                    (&hs.x)[rg] = h;
                    (&ls.x)[rg] = bf16_lo(v, h);
                }
                *(ushort4*)(pH + off) = hs;
                *(ushort4*)(pL + off) = ls;
            }
        }
    };

    auto write_out = [&](const float* cb) {
#pragma unroll
        for (int mi = 0; mi < 4; mi++) {
            const int c0 = ac + mi * 16 + quad * 4;
            const float4 cbv = *(const float4*)&cb[c0];
#pragma unroll
            for (int nj = 0; nj < 5; nj++) {
                const int node = ad + nj * 16 + l15;
                if (node < NN) {
                    float4 o;
#pragma unroll
                    for (int rg = 0; rg < 4; rg++)
                        (&o.x)[rg] = og[mi][nj][rg] + (&cbv.x)[rg];
                    *(float4*)&out[(arow0 + node) * CN + c0] = o;
                }
            }
        }
    };

    // =================== layer 0 ===================
#pragma unroll
    for (int i = 0; i < 5; i++)
#pragma unroll
        for (int j = 0; j < 4; j++) acc[i][j] = (f32x4){0.f, 0.f, 0.f, 0.f};
    stage_load(0);
    stage_write(0);
    loadW(W0_OFF, KP0, 0, 0);
    barrier_lgkm();
#pragma unroll
    for (int kt = 0; kt < 10; kt++) {       // A dbuf + W reg-dbuf
        if (kt < 9) stage_load(kt + 1);
        if (kt < 9) loadW(W0_OFF, KP0, kt + 1, (kt + 1) & 1);
        gemm_l0_tile(kt & 1, kt & 1);
        if (kt < 9) stage_write((kt + 1) & 1);
        barrier_lgkm();
    }
    write_tT();
    adj_pf(0); adj_pf(1); adj_pf(2); adj_pf(3);   // in flight across barrier
    barrier_lgkm();
    do_agg();
    barrier_lgkm();
    write_h(cb0, bw0, bb0);
    loadW(W1_OFF, CN, 0, 0);                      // in flight across barrier
    barrier_lgkm();
    // =================== layer 1 ===================
    gemm_h(W1_OFF);
    barrier_lgkm();
    write_tT();
    adj_pf(0); adj_pf(1); adj_pf(2); adj_pf(3);
    barrier_lgkm();
    do_agg();
    barrier_lgkm();
    write_h(cb1, bw1, bb1);
    loadW(W2_OFF, CN, 0, 0);
    barrier_lgkm();
    // =================== layer 2 ===================
    gemm_h(W2_OFF);
    barrier_lgkm();
    write_tT();
    adj_pf(0); adj_pf(1); adj_pf(2); adj_pf(3);
    barrier_lgkm();
    do_agg();
    write_out(cb2);
}

// ---------------------------------------------------------------------------
// Orchestration: prep_wt (Adj + scaled weight planes) + one fused kernel.
// ---------------------------------------------------------------------------
extern "C" void kernel_launch(void* const* d_in, const int* in_sizes, int n_in,
                              void* d_out, int out_size, void* d_ws, size_t ws_size,
                              hipStream_t stream) {
    const float* x    = (const float*)d_in[0];
    const int*   ei   = (const int*)  d_in[1];
    const float* W0   = (const float*)d_in[2];
    const float* b0   = (const float*)d_in[3];
    const float* bnw0 = (const float*)d_in[4];
    const float* bnb0 = (const float*)d_in[5];
    const float* W1   = (const float*)d_in[6];
    const float* b1   = (const float*)d_in[7];
    const float* bnw1 = (const float*)d_in[8];
    const float* bnb1 = (const float*)d_in[9];
    const float* W2   = (const float*)d_in[10];
    const float* b2   = (const float*)d_in[11];
    float* out = (float*)d_out;

    const int E = in_sizes[1] / 2;

    prep_wt<<<289, 256, 0, stream>>>(ei, E, W0, W1, W2, bnw0, bnw1);
    fused_all<<<BATCH, 256, 0, stream>>>(x, b0, bnw0, bnb0,
                                         b1, bnw1, bnb1, b2, out);
}